// Round 12
// baseline (47.460 us; speedup 1.0000x reference)
//
#include <hip/hip_runtime.h>
#include <hip/hip_fp16.h>
#include <math.h>

#define ALPHA 0.001f
#define GAMMA 0.01f
#define DD 784
#define TD 1568          // 2*D floats per template row
#define MM 256
#define BB 1024
#define NCLS 10
#define ROWS_PB 8
#define TPW 4            // templates per wave (fp16, register-resident)
#define NBLK 2048        // 128 rowgroups x 16 tgroups

typedef _Float16 v2h __attribute__((ext_vector_type(2)));
typedef _Float16 v8h __attribute__((ext_vector_type(8)));
typedef __fp16 f16x2 __attribute__((ext_vector_type(2)));
union H8 { v8h v; v2h p[4]; };

static __device__ __forceinline__ v2h pkrtz(float a, float b) {
  f16x2 r = __builtin_amdgcn_cvt_pkrtz(a, b);
  return __builtin_bit_cast(v2h, r);
}

// ---- DPP wave64 sum (VALU pipe, no DS traffic) ----
template <int CTRL, int RMASK>
static __device__ __forceinline__ float dpp_add(float v) {
  int t = __builtin_amdgcn_update_dpp(0, __builtin_bit_cast(int, v),
                                      CTRL, RMASK, 0xf, false);
  return v + __builtin_bit_cast(float, t);
}
static __device__ __forceinline__ float wave_sum64_lane63(float v) {
  v = dpp_add<0x111, 0xf>(v);   // row_shr:1
  v = dpp_add<0x112, 0xf>(v);   // row_shr:2
  v = dpp_add<0x114, 0xf>(v);   // row_shr:4
  v = dpp_add<0x118, 0xf>(v);   // row_shr:8
  v = dpp_add<0x142, 0xa>(v);   // row_bcast:15 -> rows 1,3
  v = dpp_add<0x143, 0xc>(v);   // row_bcast:31 -> rows 2,3
  return v;                     // lane 63 = full 64-lane sum
}

// ws layout (floats):
//   [0..255] partial min | [256..511] partial max | [512..767] scale[m]
//   [768] min | [769] 1/(max-min+1e-10)

__global__ __launch_bounds__(256) void k_minmax(const float* __restrict__ x,
                                                float* __restrict__ ws,
                                                int* __restrict__ out_bits) {
  const float4* x4 = (const float4*)x;
  const int n4 = BB * DD / 4;
  int tid = blockIdx.x * 256 + threadIdx.x;
  if (tid < BB * NCLS) out_bits[tid] = (int)0xFF800000;  // -inf each launch
  float mn = 1e30f, mx = -1e30f;
  for (int i = tid; i < n4; i += 256 * 256) {
    float4 v = x4[i];
    mn = fminf(mn, fminf(fminf(v.x, v.y), fminf(v.z, v.w)));
    mx = fmaxf(mx, fmaxf(fmaxf(v.x, v.y), fmaxf(v.z, v.w)));
  }
#pragma unroll
  for (int off = 32; off; off >>= 1) {
    mn = fminf(mn, __shfl_xor(mn, off, 64));
    mx = fmaxf(mx, __shfl_xor(mx, off, 64));
  }
  __shared__ float smn[4], smx[4];
  int lane = threadIdx.x & 63, wid = threadIdx.x >> 6;
  if (lane == 0) { smn[wid] = mn; smx[wid] = mx; }
  __syncthreads();
  if (threadIdx.x == 0) {
    mn = fminf(fminf(smn[0], smn[1]), fminf(smn[2], smn[3]));
    mx = fmaxf(fmaxf(smx[0], smx[1]), fmaxf(smx[2], smx[3]));
    ws[blockIdx.x] = mn;
    ws[256 + blockIdx.x] = mx;
  }
}

__global__ __launch_bounds__(256) void k_stats(float* __restrict__ ws) {
  int tid = threadIdx.x;
  float mn = ws[tid], mx = ws[256 + tid];
#pragma unroll
  for (int off = 32; off; off >>= 1) {
    mn = fminf(mn, __shfl_xor(mn, off, 64));
    mx = fmaxf(mx, __shfl_xor(mx, off, 64));
  }
  __shared__ float smn[4], smx[4];
  int lane = tid & 63, wid = tid >> 6;
  if (lane == 0) { smn[wid] = mn; smx[wid] = mx; }
  __syncthreads();
  if (tid == 0) {
    mn = fminf(fminf(smn[0], smn[1]), fminf(smn[2], smn[3]));
    mx = fmaxf(fmaxf(smx[0], smx[1]), fmaxf(smx[2], smx[3]));
    ws[768] = mn;
    ws[769] = 1.0f / (mx - mn + 1e-10f);
  }
}

__global__ __launch_bounds__(64) void k_denom(const float* __restrict__ T,
                                              const int* __restrict__ committed,
                                              const int* __restrict__ counts,
                                              float* __restrict__ scale_out) {
  int m = blockIdx.x;
  int lane = threadIdx.x;
  const float4* t4 = (const float4*)(T + m * TD);
  float s = 0.f;
  for (int i = lane; i < TD / 4; i += 64) {
    float4 v = t4[i];
    s += (v.x + v.y) + (v.z + v.w);
  }
#pragma unroll
  for (int off = 32; off; off >>= 1) s += __shfl_xor(s, off, 64);
  if (lane == 0) {
    float denom = ALPHA + s + GAMMA * (float)counts[m];
    scale_out[m] = committed[m] ? (1.0f / denom) : -1.0f;
  }
}

// grid: 2048 = 128 rowgroups x 16 tgroups; 256 threads = 4 waves (1/SIMD).
// Wave holds TPW=4 templates ENTIRELY in fp16 registers (16 x H8 = 64 VGPR),
// loaded in a one-shot VMEM prologue and PINNED via asm so the compiler
// cannot sink the loads into the steady loop (R11 failure: VGPR=80 proved
// it rematerialized). Steady loop = DS + VALU only (R8 NOGLB shape).
__global__ __launch_bounds__(256) void k_main(const float* __restrict__ x,
                                              const float* __restrict__ T,
                                              const int* __restrict__ labels,
                                              const float* __restrict__ ws,
                                              int* __restrict__ out_bits) {
  __shared__ v8h coded8[ROWS_PB * 256];   // 8 rows x 256 v8h x 16B = 32768 B
  __shared__ int clsmax[ROWS_PB][NCLS];

  int tid = threadIdx.x;
  int lane = tid & 63, wid = tid >> 6;
  int rg = blockIdx.x >> 4;
  int tg = blockIdx.x & 15;
  int row0 = rg * ROWS_PB;
  int m0 = tg * 16 + wid * TPW;

  float finv = ws[769];
  float fmn = ws[768];
  float na = finv, nb = -fmn * finv;     // norm: v = na*t + nb

  float scv[TPW];
  int lbv[TPW];
#pragma unroll
  for (int t = 0; t < TPW; ++t) { scv[t] = ws[512 + m0 + t]; lbv[t] = labels[m0 + t]; }

  if (tid < ROWS_PB * NCLS) clsmax[tid / NCLS][tid % NCLS] = (int)0xFF800000;

  // ---- prologue: issue template loads (fp16, 64 VGPR target) ----
  H8 tmpl[TPW][4];
#pragma unroll
  for (int t = 0; t < TPW; ++t) {
#pragma unroll
    for (int c = 0; c < 4; ++c) {
      int e = (c * 64 + lane) * 8;
      if (e > TD - 8) e = TD - 8;        // clamp tail (c=3, lane>=4); coded pad=0 kills it
      const float4* tp = (const float4*)(T + (size_t)(m0 + t) * TD + e);
      float4 fa = tp[0], fb = tp[1];
      tmpl[t][c].p[0] = pkrtz(fa.x, fa.y);
      tmpl[t][c].p[1] = pkrtz(fa.z, fa.w);
      tmpl[t][c].p[2] = pkrtz(fb.x, fb.y);
      tmpl[t][c].p[3] = pkrtz(fb.z, fb.w);
    }
  }

  // ---- stage 8 coded rows (normalized, complement-coded, zero-padded) ----
#pragma unroll
  for (int i = 0; i < 8; ++i) {
    int idx = i * 256 + tid;
    int r = idx >> 8;
    int p = idx & 255;                  // v8h index within row
    H8 u;
    if (p < 196) {
      int e = (p < 98) ? (p * 8) : ((p - 98) * 8);
      const float4* xr = (const float4*)(x + (size_t)(row0 + r) * DD + e);
      float4 fa = xr[0], fb = xr[1];
      float v0 = na * fa.x + nb, v1 = na * fa.y + nb;
      float v2 = na * fa.z + nb, v3 = na * fa.w + nb;
      float v4 = na * fb.x + nb, v5 = na * fb.y + nb;
      float v6 = na * fb.z + nb, v7 = na * fb.w + nb;
      if (p >= 98) {
        v0 = 1.f - v0; v1 = 1.f - v1; v2 = 1.f - v2; v3 = 1.f - v3;
        v4 = 1.f - v4; v5 = 1.f - v5; v6 = 1.f - v6; v7 = 1.f - v7;
      }
      u.p[0] = pkrtz(v0, v1);
      u.p[1] = pkrtz(v2, v3);
      u.p[2] = pkrtz(v4, v5);
      u.p[3] = pkrtz(v6, v7);
    } else {
      u.p[0] = pkrtz(0.f, 0.f);
      u.p[1] = pkrtz(0.f, 0.f);
      u.p[2] = pkrtz(0.f, 0.f);
      u.p[3] = pkrtz(0.f, 0.f);
    }
    coded8[idx] = u.v;
  }

  // ---- PIN: force templates materialized in VGPRs before the steady loop.
  // Loads were issued above; their waits land here, hidden under staging.
#pragma unroll
  for (int t = 0; t < TPW; ++t)
#pragma unroll
    for (int c = 0; c < 4; ++c)
      asm volatile("" : "+v"(tmpl[t][c].p[0]), "+v"(tmpl[t][c].p[1]),
                         "+v"(tmpl[t][c].p[2]), "+v"(tmpl[t][c].p[3]));

  __syncthreads();

  // ---- steady state: DS + VALU only ----
  float acc[TPW][ROWS_PB];
#pragma unroll
  for (int t = 0; t < TPW; ++t)
#pragma unroll
    for (int r = 0; r < ROWS_PB; ++r) acc[t][r] = 0.f;

  v2h ones; ones.x = (_Float16)1.f; ones.y = (_Float16)1.f;

#pragma unroll
  for (int r = 0; r < ROWS_PB; ++r) {
    H8 cv[4];
#pragma unroll
    for (int c = 0; c < 4; ++c)
      cv[c].v = coded8[r * 256 + c * 64 + lane];   // 4x ds_read_b128
#pragma unroll
    for (int c = 0; c < 4; ++c) {
#pragma unroll
      for (int t = 0; t < TPW; ++t) {
        v2h m0_ = __builtin_elementwise_min(cv[c].p[0], tmpl[t][c].p[0]);
        v2h m1_ = __builtin_elementwise_min(cv[c].p[1], tmpl[t][c].p[1]);
        v2h m2_ = __builtin_elementwise_min(cv[c].p[2], tmpl[t][c].p[2]);
        v2h m3_ = __builtin_elementwise_min(cv[c].p[3], tmpl[t][c].p[3]);
        acc[t][r] = __builtin_amdgcn_fdot2(m0_, ones, acc[t][r], false);
        acc[t][r] = __builtin_amdgcn_fdot2(m1_, ones, acc[t][r], false);
        acc[t][r] = __builtin_amdgcn_fdot2(m2_, ones, acc[t][r], false);
        acc[t][r] = __builtin_amdgcn_fdot2(m3_, ones, acc[t][r], false);
      }
    }
  }

  // ---- reduce: 32 DPP sums + readlane scatter ----
  float vout = 0.f;
#pragma unroll
  for (int t = 0; t < TPW; ++t)
#pragma unroll
    for (int r = 0; r < ROWS_PB; ++r) {
      float s = wave_sum64_lane63(acc[t][r]);
      float g = __builtin_bit_cast(float,
                  __builtin_amdgcn_readlane(__builtin_bit_cast(int, s), 63));
      if (lane == t * 8 + r) vout = g;
    }

  float sc = -1.f; int lb = 0;
#pragma unroll
  for (int t = 0; t < TPW; ++t)
    if ((lane >> 3) == t) { sc = scv[t]; lb = lbv[t]; }
  if (lane < 32 && sc > 0.f)
    atomicMax(&clsmax[lane & 7][lb], __float_as_int(vout * sc));
  __syncthreads();

  if (tid < ROWS_PB * NCLS) {
    int rr = tid / NCLS, cc = tid - rr * NCLS;
    int bits = clsmax[rr][cc];
    if (bits != (int)0xFF800000)
      atomicMax(&out_bits[(row0 + rr) * NCLS + cc], bits);
  }
}

extern "C" void kernel_launch(void* const* d_in, const int* in_sizes, int n_in,
                              void* d_out, int out_size, void* d_ws, size_t ws_size,
                              hipStream_t stream) {
  const float* x = (const float*)d_in[0];
  const float* T = (const float*)d_in[1];
  const int* committed = (const int*)d_in[2];
  const int* labels = (const int*)d_in[3];
  const int* counts = (const int*)d_in[4];
  int* out_bits = (int*)d_out;
  float* ws = (float*)d_ws;

  k_minmax<<<dim3(256), dim3(256), 0, stream>>>(x, ws, out_bits);
  k_stats<<<dim3(1), dim3(256), 0, stream>>>(ws);
  k_denom<<<dim3(256), dim3(64), 0, stream>>>(T, committed, counts, ws + 512);
  k_main<<<dim3(NBLK), dim3(256), 0, stream>>>(x, T, labels, ws, out_bits);
}

// Round 13
// 33.209 us; speedup vs baseline: 1.4292x; 1.4292x over previous
//
#include <hip/hip_runtime.h>
#include <math.h>

#define ALPHA 0.001f
#define GAMMA 0.01f
#define DD 784
#define TD 1568          // 2*D floats per template row
#define RB 2048          // padded u8 row bytes (coded & templates)
#define MM 256
#define BB 1024
#define NCLS 10
#define ROWS_PB 8
#define TPW 4
#define NBLK 2048        // 128 rowgroups x 16 tgroups

// ws layout:
//   f32[0..255] partial min | f32[256..511] partial max
//   f32[512..767] scale[m] = committed ? 1/denom : -1
//   f32[768] min, f32[769] 1/(max-min+1e-10)
//   i32[1024..1279] tsum[m]  (int sum of quantized template bytes)
//   byte offset 8192: u8 templates, 256 rows x 2048 B = 512 KB

static __device__ __forceinline__ unsigned sad_u8(unsigned a, unsigned b, unsigned c) {
  unsigned d;
  asm("v_sad_u8 %0, %1, %2, %3" : "=v"(d) : "v"(a), "v"(b), "v"(c));
  return d;
}

template <int CTRL, int RMASK>
static __device__ __forceinline__ int dpp_iadd(int v) {
  int t = __builtin_amdgcn_update_dpp(0, v, CTRL, RMASK, 0xf, false);
  return v + t;
}
static __device__ __forceinline__ int wave_isum64_lane63(int v) {
  v = dpp_iadd<0x111, 0xf>(v);   // row_shr:1
  v = dpp_iadd<0x112, 0xf>(v);   // row_shr:2
  v = dpp_iadd<0x114, 0xf>(v);   // row_shr:4
  v = dpp_iadd<0x118, 0xf>(v);   // row_shr:8
  v = dpp_iadd<0x142, 0xa>(v);   // row_bcast:15 -> rows 1,3
  v = dpp_iadd<0x143, 0xc>(v);   // row_bcast:31 -> rows 2,3
  return v;                      // lane 63 = full sum
}

static __device__ __forceinline__ unsigned q8(float v) {
  return (unsigned)(v * 255.f + 0.5f);   // v in [0,1]
}

__global__ __launch_bounds__(256) void k_minmax(const float* __restrict__ x,
                                                float* __restrict__ ws,
                                                int* __restrict__ out_bits) {
  const float4* x4 = (const float4*)x;
  const int n4 = BB * DD / 4;
  int tid = blockIdx.x * 256 + threadIdx.x;
  if (tid < BB * NCLS) out_bits[tid] = (int)0xFF800000;  // -inf each launch
  float mn = 1e30f, mx = -1e30f;
  for (int i = tid; i < n4; i += 256 * 256) {
    float4 v = x4[i];
    mn = fminf(mn, fminf(fminf(v.x, v.y), fminf(v.z, v.w)));
    mx = fmaxf(mx, fmaxf(fmaxf(v.x, v.y), fmaxf(v.z, v.w)));
  }
#pragma unroll
  for (int off = 32; off; off >>= 1) {
    mn = fminf(mn, __shfl_xor(mn, off, 64));
    mx = fmaxf(mx, __shfl_xor(mx, off, 64));
  }
  __shared__ float smn[4], smx[4];
  int lane = threadIdx.x & 63, wid = threadIdx.x >> 6;
  if (lane == 0) { smn[wid] = mn; smx[wid] = mx; }
  __syncthreads();
  if (threadIdx.x == 0) {
    mn = fminf(fminf(smn[0], smn[1]), fminf(smn[2], smn[3]));
    mx = fmaxf(fmaxf(smx[0], smx[1]), fmaxf(smx[2], smx[3]));
    ws[blockIdx.x] = mn;
    ws[256 + blockIdx.x] = mx;
  }
}

__global__ __launch_bounds__(256) void k_stats(float* __restrict__ ws) {
  int tid = threadIdx.x;
  float mn = ws[tid], mx = ws[256 + tid];
#pragma unroll
  for (int off = 32; off; off >>= 1) {
    mn = fminf(mn, __shfl_xor(mn, off, 64));
    mx = fmaxf(mx, __shfl_xor(mx, off, 64));
  }
  __shared__ float smn[4], smx[4];
  int lane = tid & 63, wid = tid >> 6;
  if (lane == 0) { smn[wid] = mn; smx[wid] = mx; }
  __syncthreads();
  if (tid == 0) {
    mn = fminf(fminf(smn[0], smn[1]), fminf(smn[2], smn[3]));
    mx = fmaxf(fmaxf(smx[0], smx[1]), fmaxf(smx[2], smx[3]));
    ws[768] = mn;
    ws[769] = 1.0f / (mx - mn + 1e-10f);
  }
}

// block per template m, 64 threads. Lane l covers elements 32l..32l+31
// (lanes 0..48 have data; 49..63 zero-pad). Emits: f32 scale, int tsum,
// and the quantized+packed u8 template row (2048 B).
__global__ __launch_bounds__(64) void k_denom(const float* __restrict__ T,
                                              const int* __restrict__ committed,
                                              const int* __restrict__ counts,
                                              float* __restrict__ ws) {
  int m = blockIdx.x;
  int lane = threadIdx.x;
  float s = 0.f;
  int isum = 0;
  uint4 pk[2] = {make_uint4(0,0,0,0), make_uint4(0,0,0,0)};
  if (lane < 49) {
    const float4* tp = (const float4*)(T + (size_t)m * TD + lane * 32);
    unsigned w[8];
#pragma unroll
    for (int d = 0; d < 8; ++d) {
      float4 f = tp[d];
      s += (f.x + f.y) + (f.z + f.w);
      unsigned b0 = q8(f.x), b1 = q8(f.y), b2 = q8(f.z), b3 = q8(f.w);
      isum += (int)(b0 + b1 + b2 + b3);
      w[d] = b0 | (b1 << 8) | (b2 << 16) | (b3 << 24);
    }
    pk[0] = make_uint4(w[0], w[1], w[2], w[3]);
    pk[1] = make_uint4(w[4], w[5], w[6], w[7]);
  }
  uint4* u8T = (uint4*)((char*)ws + 8192 + (size_t)m * RB);
  u8T[lane * 2]     = pk[0];
  u8T[lane * 2 + 1] = pk[1];
#pragma unroll
  for (int off = 32; off; off >>= 1) {
    s += __shfl_xor(s, off, 64);
    isum += __shfl_xor(isum, off, 64);
  }
  if (lane == 0) {
    float denom = ALPHA + s + GAMMA * (float)counts[m];
    ws[512 + m] = committed[m] ? (1.0f / denom) : -1.0f;
    ((int*)ws)[1024 + m] = isum;
  }
}

// grid: 2048 = 128 rowgroups x 16 tgroups; 256 threads = 4 waves.
// Wave owns TPW=4 templates as u8 in registers (8 dwords/lane/template = 32
// VGPR total). Block stages 8 coded rows as u8 in LDS (2048 B each, 16.5 KB).
// Steady loop per row: 2 ds_read_b128 + 32 v_sad_u8. Exact int identity:
// 2*Sum(min) = rowsum + tsum - SAD.
__global__ __launch_bounds__(256, 4) void k_main(const float* __restrict__ x,
                                                 const int* __restrict__ labels,
                                                 const float* __restrict__ ws,
                                                 int* __restrict__ out_bits) {
  __shared__ uint4 coded[ROWS_PB * 128];   // 8 rows x 2048 B = 16384 B
  __shared__ int rowsum[ROWS_PB];
  __shared__ int clsmax[ROWS_PB][NCLS];

  int tid = threadIdx.x;
  int lane = tid & 63, wid = tid >> 6;
  int rg = blockIdx.x >> 4;
  int tg = blockIdx.x & 15;
  int row0 = rg * ROWS_PB;
  int m0 = tg * 16 + wid * TPW;

  float fmn = ws[768], finv = ws[769];
  float na = finv, nb = -fmn * finv;

  float scv[TPW];
  int lbv[TPW], tsv[TPW];
#pragma unroll
  for (int t = 0; t < TPW; ++t) {
    scv[t] = ws[512 + m0 + t];
    lbv[t] = labels[m0 + t];
    tsv[t] = ((const int*)ws)[1024 + m0 + t];
  }

  // ---- template u8 rows -> registers (8 dwords each = 32 VGPR total) ----
  uint4 tr[TPW][2];
#pragma unroll
  for (int t = 0; t < TPW; ++t) {
    const uint4* tp = (const uint4*)((const char*)ws + 8192 + (size_t)(m0 + t) * RB);
    tr[t][0] = tp[lane];
    tr[t][1] = tp[64 + lane];
  }

  if (tid < ROWS_PB * NCLS) clsmax[tid / NCLS][tid % NCLS] = (int)0xFF800000;
  if (tid < ROWS_PB) rowsum[tid] = 0;
  __syncthreads();

  // ---- stage 8 coded rows as quantized u8 (1024 uint4, 4 per thread) ----
#pragma unroll
  for (int i = 0; i < 4; ++i) {
    int idx = i * 256 + tid;
    int r = idx >> 7;
    int u = idx & 127;                 // uint4 index within row
    uint4 out = make_uint4(0, 0, 0, 0);
    if (u < 98) {
      int half = (u >= 49);
      int e = (half ? (u - 49) : u) * 16;
      const float4* xr = (const float4*)(x + (size_t)(row0 + r) * DD + e);
      unsigned w[4];
      int isum = 0;
#pragma unroll
      for (int d = 0; d < 4; ++d) {
        float4 f = xr[d];
        float v0 = na * f.x + nb, v1 = na * f.y + nb;
        float v2 = na * f.z + nb, v3 = na * f.w + nb;
        if (half) { v0 = 1.f - v0; v1 = 1.f - v1; v2 = 1.f - v2; v3 = 1.f - v3; }
        unsigned b0 = q8(v0), b1 = q8(v1), b2 = q8(v2), b3 = q8(v3);
        isum += (int)(b0 + b1 + b2 + b3);
        w[d] = b0 | (b1 << 8) | (b2 << 16) | (b3 << 24);
      }
      out = make_uint4(w[0], w[1], w[2], w[3]);
      atomicAdd(&rowsum[r], isum);
    }
    coded[idx] = out;
  }
  __syncthreads();

  // ---- steady loop: per row 2 ds_read_b128 + 32 v_sad_u8 ----
  unsigned acc[TPW][ROWS_PB];
#pragma unroll
  for (int t = 0; t < TPW; ++t)
#pragma unroll
    for (int r = 0; r < ROWS_PB; ++r) acc[t][r] = 0;

#pragma unroll
  for (int r = 0; r < ROWS_PB; ++r) {
    uint4 c0 = coded[r * 128 + lane];
    uint4 c1 = coded[r * 128 + 64 + lane];
#pragma unroll
    for (int t = 0; t < TPW; ++t) {
      unsigned a = acc[t][r];
      a = sad_u8(c0.x, tr[t][0].x, a);
      a = sad_u8(c0.y, tr[t][0].y, a);
      a = sad_u8(c0.z, tr[t][0].z, a);
      a = sad_u8(c0.w, tr[t][0].w, a);
      a = sad_u8(c1.x, tr[t][1].x, a);
      a = sad_u8(c1.y, tr[t][1].y, a);
      a = sad_u8(c1.z, tr[t][1].z, a);
      a = sad_u8(c1.w, tr[t][1].w, a);
      acc[t][r] = a;
    }
  }

  // ---- reduce: int DPP sums; scatter lane = t*8+r computes choice ----
  int myrow = rowsum[lane & 7];        // for scatter lane: r = lane&7
  float sc = -1.f; int lb = 0, tsum_s = 0;
#pragma unroll
  for (int t = 0; t < TPW; ++t)
    if ((lane >> 3) == t) { sc = scv[t]; lb = lbv[t]; tsum_s = tsv[t]; }

  float vout = 0.f;
#pragma unroll
  for (int t = 0; t < TPW; ++t)
#pragma unroll
    for (int r = 0; r < ROWS_PB; ++r) {
      int s = wave_isum64_lane63((int)acc[t][r]);
      int g = __builtin_amdgcn_readlane(s, 63);
      if (lane == t * 8 + r)
        vout = (float)(myrow + tsum_s - g) * (sc * (0.5f / 255.f));
    }

  if (lane < 32 && sc > 0.f)
    atomicMax(&clsmax[lane & 7][lb], __float_as_int(vout));
  __syncthreads();

  if (tid < ROWS_PB * NCLS) {
    int rr = tid / NCLS, cc = tid - rr * NCLS;
    int bits = clsmax[rr][cc];
    if (bits != (int)0xFF800000)
      atomicMax(&out_bits[(row0 + rr) * NCLS + cc], bits);
  }
}

extern "C" void kernel_launch(void* const* d_in, const int* in_sizes, int n_in,
                              void* d_out, int out_size, void* d_ws, size_t ws_size,
                              hipStream_t stream) {
  const float* x = (const float*)d_in[0];
  const float* T = (const float*)d_in[1];
  const int* committed = (const int*)d_in[2];
  const int* labels = (const int*)d_in[3];
  const int* counts = (const int*)d_in[4];
  int* out_bits = (int*)d_out;
  float* ws = (float*)d_ws;

  k_minmax<<<dim3(256), dim3(256), 0, stream>>>(x, ws, out_bits);
  k_stats<<<dim3(1), dim3(256), 0, stream>>>(ws);
  k_denom<<<dim3(256), dim3(64), 0, stream>>>(T, committed, counts, ws);
  k_main<<<dim3(NBLK), dim3(256), 0, stream>>>(x, labels, ws, out_bits);
}

// Round 14
// 31.381 us; speedup vs baseline: 1.5124x; 1.0582x over previous
//
#include <hip/hip_runtime.h>
#include <math.h>

#define ALPHA 0.001f
#define GAMMA 0.01f
#define DD 784
#define TD 1568          // 2*D floats per template row
#define RB 2048          // padded u8 row bytes (coded & templates)
#define MM 256
#define BB 1024
#define NCLS 10
#define ROWS_PB 8
#define TPW 4
#define NBLK 2048        // 128 rowgroups x 16 tgroups

// ws layout:
//   f32[0..255] partial min | f32[256..511] partial max
//   f32[512..767] scale[m] | f32[768] min | f32[769] 1/(max-min+1e-10)
//   i32[1024..1279] tsum[m]
//   i32[1536..2559] rowsum[row]           (bytes 6144..10240)
//   byte 16384:  u8 templates 256 x 2048  (512 KB)
//   byte 540672: u8 coded    1024 x 2048  (2 MB)   -> total ~2.52 MB

#define TMPL_OFF 16384
#define CODED_OFF 540672

static __device__ __forceinline__ unsigned sad_u8(unsigned a, unsigned b, unsigned c) {
  unsigned d;
  asm("v_sad_u8 %0, %1, %2, %3" : "=v"(d) : "v"(a), "v"(b), "v"(c));
  return d;
}

template <int CTRL, int RMASK>
static __device__ __forceinline__ int dpp_iadd(int v) {
  int t = __builtin_amdgcn_update_dpp(0, v, CTRL, RMASK, 0xf, false);
  return v + t;
}
static __device__ __forceinline__ int wave_isum64_lane63(int v) {
  v = dpp_iadd<0x111, 0xf>(v);   // row_shr:1
  v = dpp_iadd<0x112, 0xf>(v);   // row_shr:2
  v = dpp_iadd<0x114, 0xf>(v);   // row_shr:4
  v = dpp_iadd<0x118, 0xf>(v);   // row_shr:8
  v = dpp_iadd<0x142, 0xa>(v);   // row_bcast:15 -> rows 1,3
  v = dpp_iadd<0x143, 0xc>(v);   // row_bcast:31 -> rows 2,3
  return v;                      // lane 63 = full sum
}

static __device__ __forceinline__ unsigned q8(float v) {
  return (unsigned)(v * 255.f + 0.5f);   // v in [0,1]
}

__global__ __launch_bounds__(256) void k_minmax(const float* __restrict__ x,
                                                float* __restrict__ ws,
                                                int* __restrict__ out_bits) {
  const float4* x4 = (const float4*)x;
  const int n4 = BB * DD / 4;
  int tid = blockIdx.x * 256 + threadIdx.x;
  if (tid < BB * NCLS) out_bits[tid] = (int)0xFF800000;  // -inf each launch
  float mn = 1e30f, mx = -1e30f;
  for (int i = tid; i < n4; i += 256 * 256) {
    float4 v = x4[i];
    mn = fminf(mn, fminf(fminf(v.x, v.y), fminf(v.z, v.w)));
    mx = fmaxf(mx, fmaxf(fmaxf(v.x, v.y), fmaxf(v.z, v.w)));
  }
#pragma unroll
  for (int off = 32; off; off >>= 1) {
    mn = fminf(mn, __shfl_xor(mn, off, 64));
    mx = fmaxf(mx, __shfl_xor(mx, off, 64));
  }
  __shared__ float smn[4], smx[4];
  int lane = threadIdx.x & 63, wid = threadIdx.x >> 6;
  if (lane == 0) { smn[wid] = mn; smx[wid] = mx; }
  __syncthreads();
  if (threadIdx.x == 0) {
    mn = fminf(fminf(smn[0], smn[1]), fminf(smn[2], smn[3]));
    mx = fmaxf(fmaxf(smx[0], smx[1]), fmaxf(smx[2], smx[3]));
    ws[blockIdx.x] = mn;
    ws[256 + blockIdx.x] = mx;
  }
}

__global__ __launch_bounds__(256) void k_stats(float* __restrict__ ws) {
  int tid = threadIdx.x;
  float mn = ws[tid], mx = ws[256 + tid];
#pragma unroll
  for (int off = 32; off; off >>= 1) {
    mn = fminf(mn, __shfl_xor(mn, off, 64));
    mx = fmaxf(mx, __shfl_xor(mx, off, 64));
  }
  __shared__ float smn[4], smx[4];
  int lane = tid & 63, wid = tid >> 6;
  if (lane == 0) { smn[wid] = mn; smx[wid] = mx; }
  __syncthreads();
  if (tid == 0) {
    mn = fminf(fminf(smn[0], smn[1]), fminf(smn[2], smn[3]));
    mx = fmaxf(fmaxf(smx[0], smx[1]), fmaxf(smx[2], smx[3]));
    ws[768] = mn;
    ws[769] = 1.0f / (mx - mn + 1e-10f);
  }
}

// block per template m, 64 threads. Emits f32 scale, int tsum, u8 row.
__global__ __launch_bounds__(64) void k_denom(const float* __restrict__ T,
                                              const int* __restrict__ committed,
                                              const int* __restrict__ counts,
                                              float* __restrict__ ws) {
  int m = blockIdx.x;
  int lane = threadIdx.x;
  float s = 0.f;
  int isum = 0;
  uint4 pk[2] = {make_uint4(0,0,0,0), make_uint4(0,0,0,0)};
  if (lane < 49) {
    const float4* tp = (const float4*)(T + (size_t)m * TD + lane * 32);
    unsigned w[8];
#pragma unroll
    for (int d = 0; d < 8; ++d) {
      float4 f = tp[d];
      s += (f.x + f.y) + (f.z + f.w);
      unsigned b0 = q8(f.x), b1 = q8(f.y), b2 = q8(f.z), b3 = q8(f.w);
      isum += (int)(b0 + b1 + b2 + b3);
      w[d] = b0 | (b1 << 8) | (b2 << 16) | (b3 << 24);
    }
    pk[0] = make_uint4(w[0], w[1], w[2], w[3]);
    pk[1] = make_uint4(w[4], w[5], w[6], w[7]);
  }
  uint4* u8T = (uint4*)((char*)ws + TMPL_OFF + (size_t)m * RB);
  u8T[lane * 2]     = pk[0];
  u8T[lane * 2 + 1] = pk[1];
#pragma unroll
  for (int off = 32; off; off >>= 1) {
    s += __shfl_xor(s, off, 64);
    isum += __shfl_xor(isum, off, 64);
  }
  if (lane == 0) {
    float denom = ALPHA + s + GAMMA * (float)counts[m];
    ws[512 + m] = committed[m] ? (1.0f / denom) : -1.0f;
    ((int*)ws)[1024 + m] = isum;
  }
}

// One-shot quantize+pack of coded x rows. 256 blocks x 256 thr; block owns
// 4 rows (512 uint4). Emits u8 coded rows + per-row int sums.
__global__ __launch_bounds__(256) void k_code(const float* __restrict__ x,
                                              float* __restrict__ ws) {
  __shared__ int rsum[4];
  int tid = threadIdx.x;
  if (tid < 4) rsum[tid] = 0;
  __syncthreads();
  float fmn = ws[768], finv = ws[769];
  float na = finv, nb = -fmn * finv;
  int row0 = blockIdx.x * 4;
  uint4* out4 = (uint4*)((char*)ws + CODED_OFF) + (size_t)blockIdx.x * 512;
#pragma unroll
  for (int i = 0; i < 2; ++i) {
    int idx = i * 256 + tid;           // 0..511
    int r = idx >> 7;
    int u = idx & 127;
    uint4 o = make_uint4(0, 0, 0, 0);
    if (u < 98) {
      int half = (u >= 49);
      int e = (half ? (u - 49) : u) * 16;
      const float4* xr = (const float4*)(x + (size_t)(row0 + r) * DD + e);
      unsigned w[4];
      int isum = 0;
#pragma unroll
      for (int d = 0; d < 4; ++d) {
        float4 f = xr[d];
        float v0 = na * f.x + nb, v1 = na * f.y + nb;
        float v2 = na * f.z + nb, v3 = na * f.w + nb;
        if (half) { v0 = 1.f - v0; v1 = 1.f - v1; v2 = 1.f - v2; v3 = 1.f - v3; }
        unsigned b0 = q8(v0), b1 = q8(v1), b2 = q8(v2), b3 = q8(v3);
        isum += (int)(b0 + b1 + b2 + b3);
        w[d] = b0 | (b1 << 8) | (b2 << 16) | (b3 << 24);
      }
      o = make_uint4(w[0], w[1], w[2], w[3]);
      atomicAdd(&rsum[r], isum);
    }
    out4[idx] = o;
  }
  __syncthreads();
  if (tid < 4) ((int*)ws)[1536 + row0 + tid] = rsum[tid];
}

// grid: 2048 = 128 rowgroups x 16 tgroups; 256 threads = 4 waves.
// All operands pre-quantized u8. Staging = 4 coalesced uint4 copies/thread
// (no VALU transform). Steady loop per row: 2 ds_read_b128 + 32 v_sad_u8.
// 2*Sum(min) = rowsum + tsum - SAD (exact int identity).
__global__ __launch_bounds__(256, 4) void k_main(const int* __restrict__ labels,
                                                 const float* __restrict__ ws,
                                                 int* __restrict__ out_bits) {
  __shared__ uint4 coded[ROWS_PB * 128];   // 16384 B
  __shared__ int clsmax[ROWS_PB][NCLS];

  int tid = threadIdx.x;
  int lane = tid & 63, wid = tid >> 6;
  int rg = blockIdx.x >> 4;
  int tg = blockIdx.x & 15;
  int row0 = rg * ROWS_PB;
  int m0 = tg * 16 + wid * TPW;

  float scv[TPW];
  int lbv[TPW], tsv[TPW];
#pragma unroll
  for (int t = 0; t < TPW; ++t) {
    scv[t] = ws[512 + m0 + t];
    lbv[t] = labels[m0 + t];
    tsv[t] = ((const int*)ws)[1024 + m0 + t];
  }

  // ---- template u8 rows -> registers (8 dwords each = 32 VGPR total) ----
  uint4 tr[TPW][2];
#pragma unroll
  for (int t = 0; t < TPW; ++t) {
    const uint4* tp = (const uint4*)((const char*)ws + TMPL_OFF + (size_t)(m0 + t) * RB);
    tr[t][0] = tp[lane];
    tr[t][1] = tp[64 + lane];
  }

  if (tid < ROWS_PB * NCLS) clsmax[tid / NCLS][tid % NCLS] = (int)0xFF800000;

  // ---- stage 8 coded rows: pure copy, coalesced ----
  const uint4* cg = (const uint4*)((const char*)ws + CODED_OFF) + (size_t)row0 * 128;
#pragma unroll
  for (int i = 0; i < 4; ++i) {
    int idx = i * 256 + tid;
    coded[idx] = cg[idx];
  }
  __syncthreads();

  // ---- steady loop: per row 2 ds_read_b128 + 32 v_sad_u8 ----
  unsigned acc[TPW][ROWS_PB];
#pragma unroll
  for (int t = 0; t < TPW; ++t)
#pragma unroll
    for (int r = 0; r < ROWS_PB; ++r) acc[t][r] = 0;

#pragma unroll
  for (int r = 0; r < ROWS_PB; ++r) {
    uint4 c0 = coded[r * 128 + lane];
    uint4 c1 = coded[r * 128 + 64 + lane];
#pragma unroll
    for (int t = 0; t < TPW; ++t) {
      unsigned a = acc[t][r];
      a = sad_u8(c0.x, tr[t][0].x, a);
      a = sad_u8(c0.y, tr[t][0].y, a);
      a = sad_u8(c0.z, tr[t][0].z, a);
      a = sad_u8(c0.w, tr[t][0].w, a);
      a = sad_u8(c1.x, tr[t][1].x, a);
      a = sad_u8(c1.y, tr[t][1].y, a);
      a = sad_u8(c1.z, tr[t][1].z, a);
      a = sad_u8(c1.w, tr[t][1].w, a);
      acc[t][r] = a;
    }
  }

  // ---- reduce: int DPP sums; scatter lane = t*8+r computes choice ----
  int myrow = ((const int*)ws)[1536 + row0 + (lane & 7)];
  float sc = -1.f; int lb = 0, tsum_s = 0;
#pragma unroll
  for (int t = 0; t < TPW; ++t)
    if ((lane >> 3) == t) { sc = scv[t]; lb = lbv[t]; tsum_s = tsv[t]; }

  float vout = 0.f;
#pragma unroll
  for (int t = 0; t < TPW; ++t)
#pragma unroll
    for (int r = 0; r < ROWS_PB; ++r) {
      int s = wave_isum64_lane63((int)acc[t][r]);
      int g = __builtin_amdgcn_readlane(s, 63);
      if (lane == t * 8 + r)
        vout = (float)(myrow + tsum_s - g) * (sc * (0.5f / 255.f));
    }

  if (lane < 32 && sc > 0.f)
    atomicMax(&clsmax[lane & 7][lb], __float_as_int(vout));
  __syncthreads();

  if (tid < ROWS_PB * NCLS) {
    int rr = tid / NCLS, cc = tid - rr * NCLS;
    int bits = clsmax[rr][cc];
    if (bits != (int)0xFF800000)
      atomicMax(&out_bits[(row0 + rr) * NCLS + cc], bits);
  }
}

extern "C" void kernel_launch(void* const* d_in, const int* in_sizes, int n_in,
                              void* d_out, int out_size, void* d_ws, size_t ws_size,
                              hipStream_t stream) {
  const float* x = (const float*)d_in[0];
  const float* T = (const float*)d_in[1];
  const int* committed = (const int*)d_in[2];
  const int* labels = (const int*)d_in[3];
  const int* counts = (const int*)d_in[4];
  int* out_bits = (int*)d_out;
  float* ws = (float*)d_ws;

  k_minmax<<<dim3(256), dim3(256), 0, stream>>>(x, ws, out_bits);
  k_stats<<<dim3(1), dim3(256), 0, stream>>>(ws);
  k_denom<<<dim3(256), dim3(64), 0, stream>>>(T, committed, counts, ws);
  k_code<<<dim3(256), dim3(256), 0, stream>>>(x, ws);
  k_main<<<dim3(NBLK), dim3(256), 0, stream>>>(labels, ws, out_bits);
}